// Round 4
// baseline (161.838 us; speedup 1.0000x reference)
//
#include <hip/hip_runtime.h>
#include <stdint.h>

typedef _Float16 f16;
typedef _Float16 half8 __attribute__((ext_vector_type(8)));
typedef _Float16 half4 __attribute__((ext_vector_type(4)));
typedef float floatx4 __attribute__((ext_vector_type(4)));

#define LOG2E 1.44269504088896340736f

// async global->LDS, 16B per lane. LDS dest must be wave-uniform base + lane*16.
__device__ __forceinline__ void async_cp16(const void* g, void* l) {
  __builtin_amdgcn_global_load_lds((const __attribute__((address_space(1))) void*)g,
                                   (__attribute__((address_space(3))) void*)l, 16, 0, 0);
}

// ---------------- fused prep: x transpose->fp16 + weight convert ----------------
// blocks 0..575: x [b][c][hw] fp32 -> XT [t=b*576+hw][c] fp16
// blocks 576..703: wqkv/wproj fp32 -> fp16 (q rows scaled by 0.125*log2e)
__global__ __launch_bounds__(256) void k_prep(const float* __restrict__ x,
                                              f16* __restrict__ XT,
                                              const float* __restrict__ wqkv,
                                              const float* __restrict__ wproj,
                                              f16* __restrict__ WQ, f16* __restrict__ WP) {
  __shared__ f16 sT[64][72];
  const int bid = blockIdx.x;
  const int tid = threadIdx.x;
  if (bid < 576) {
    const int hw0 = (bid % 9) * 64, c0 = ((bid / 9) & 7) * 64, b = bid / 72;
    const int cc = tid >> 6, hwc = tid & 63;
    const float* xb = x + (size_t)b * 294912;
    for (int i = 0; i < 16; ++i) {
      int c = c0 + i * 4 + cc;
      sT[hwc][i * 4 + cc] = (f16)xb[c * 576 + hw0 + hwc];
    }
    __syncthreads();
    const int c_c = tid & 63, rr = tid >> 6;
    f16* xtb = XT + ((size_t)b * 576 + hw0) * 512 + c0;
    for (int j = 0; j < 16; ++j) {
      int r = j * 4 + rr;
      xtb[(size_t)r * 512 + c_c] = sT[r][c_c];
    }
  } else {
    const float SCALE_Q = 0.125f * LOG2E;
    const int total1 = 1536 * 512, total2 = 512 * 512;
    for (int idx = (bid - 576) * 256 + tid; idx < total1 + total2; idx += 128 * 256) {
      if (idx < total1) {
        int row = idx >> 9;
        float v = wqkv[idx];
        if ((row % 192) < 64) v *= SCALE_Q;
        WQ[idx] = (f16)v;
      } else {
        WP[idx - total1] = (f16)wproj[idx - total1];
      }
    }
  }
}

// ---------------- QKV GEMM: D[t][row] = XT[t][:] . WQ[row][:] ----------------
// 128x128 tile. Q/K scattered as [gh][n][d]; V written DIRECTLY as [gh][d][n]
// via an LDS transpose in the epilogue (smem reused after the K-loop).
__global__ __launch_bounds__(256) void k_qkv_gemm(const f16* __restrict__ XT,
                                                  const f16* __restrict__ WQ,
                                                  f16* __restrict__ Qh, f16* __restrict__ Kh,
                                                  f16* __restrict__ Vh) {
  const int t0 = blockIdx.x * 128, n0 = blockIdx.y * 128;
  __shared__ alignas(16) f16 smem[2 * 128 * 64];  // sA | sB, reused as sVT in epilogue
  f16* sA = smem;
  f16* sB = smem + 128 * 64;
  const int tid = threadIdx.x;
  const int wave = tid >> 6, lane = tid & 63, quad = lane >> 4, l16 = lane & 15;
  const int msub = (wave & 1) * 64, nsub = (wave >> 1) * 64;
  const floatx4 fzero = {0.f, 0.f, 0.f, 0.f};
  floatx4 acc[4][4];
  for (int i = 0; i < 4; ++i)
    for (int j = 0; j < 4; ++j) acc[i][j] = fzero;

  for (int k0 = 0; k0 < 512; k0 += 64) {
    __syncthreads();
    for (int p = 0; p < 4; ++p) {
      int e = p * 256 + tid;
      int row = e >> 3, colb = e & 7;
      async_cp16((const char*)XT + ((size_t)(t0 + row) * 512 + k0 + colb * 8) * 2,
                 (char*)sA + e * 16);
      async_cp16((const char*)WQ + ((size_t)(n0 + row) * 512 + k0 + colb * 8) * 2,
                 (char*)sB + e * 16);
    }
    __syncthreads();
    for (int f = 0; f < 2; ++f) {
      half8 a[4], bfr[4];
      for (int ms = 0; ms < 4; ++ms)
        a[ms] = *(const half8*)&sA[(msub + ms * 16 + l16) * 64 + f * 32 + quad * 8];
      for (int ns = 0; ns < 4; ++ns)
        bfr[ns] = *(const half8*)&sB[(nsub + ns * 16 + l16) * 64 + f * 32 + quad * 8];
      for (int ms = 0; ms < 4; ++ms)
        for (int ns = 0; ns < 4; ++ns)
          acc[ms][ns] =
              __builtin_amdgcn_mfma_f32_16x16x32_f16(a[ms], bfr[ns], acc[ms][ns], 0, 0, 0);
    }
  }
  // Q/K scatter (sel 0/1 only)
  for (int ms = 0; ms < 4; ++ms) {
    int tbase = t0 + msub + ms * 16 + quad * 4;
    for (int ns = 0; ns < 4; ++ns) {
      int row = n0 + nsub + ns * 16 + l16;
      int h = row / 192, rr2 = row % 192;
      int sel = rr2 >> 6, d = rr2 & 63;
      if (sel == 2) continue;
      for (int r = 0; r < 4; ++r) {
        int t = tbase + r;
        int b = t / 576, hw = t % 576;
        int g = b >> 2, v = b & 3;
        int n = v * 576 + hw;
        int gh = g * 8 + h;
        f16 hv = (f16)acc[ms][ns][r];
        size_t idx = ((size_t)gh * 2304 + n) * 64 + d;
        if (sel == 0)
          Qh[idx] = hv;
        else
          Kh[idx] = hv;
      }
    }
  }
  // V: LDS transpose [d][tok] then coalesced [gh][d][n] stores
  const int r0 = n0 % 192;  // 0: no V rows; 128: local rows [0,64); 64: local rows [64,128)
  if (r0 != 0) {
    const int vloc = (r0 == 128) ? 0 : 64;
    const int h = (n0 + vloc) / 192;
    f16* sVT = smem;  // stride 136 (16B-aligned rows), 64*136 = 8704 elems < 16384
    __syncthreads();
    if ((wave >> 1) == (vloc >> 6)) {
      for (int ms = 0; ms < 4; ++ms) {
        int tok = msub + ms * 16 + quad * 4;
        for (int ns = 0; ns < 4; ++ns) {
          int d = ns * 16 + l16;
          half4 hv;
          for (int r = 0; r < 4; ++r) hv[r] = (f16)acc[ms][ns][r];
          *(half4*)&sVT[d * 136 + tok] = hv;
        }
      }
    }
    __syncthreads();
    for (int pss = 0; pss < 4; ++pss) {
      int d = pss * 16 + (tid >> 4), chunk = tid & 15;
      int t = t0 + chunk * 8;
      int b = t / 576, hw = t - b * 576;
      int gh = (b >> 2) * 8 + h, n = (b & 3) * 576 + hw;
      *(half8*)(Vh + (size_t)gh * 147456 + (size_t)d * 2304 + n) =
          *(const half8*)&sVT[d * 136 + chunk * 8];
    }
  }
}

// ---------------- flash attention per (g,h, 64-query tile) ----------------
// 2 waves x 32 queries: K/V fragments read once, used by 2 m-subtiles.
// S^T via swapped MFMA -> P stays in registers (K=16 A-layout). XOR-swizzled LDS.
__global__ __launch_bounds__(128) void k_attn(const f16* __restrict__ Qh,
                                              const f16* __restrict__ Kh,
                                              const f16* __restrict__ Vh,
                                              f16* __restrict__ AOT) {
  const int mt = blockIdx.x, gh = blockIdx.y;
  const int m0 = mt * 64;
  const int g = gh >> 3, h = gh & 7;
  const f16* Qg = Qh + (size_t)gh * 147456;  // [n][d]
  const f16* Kg = Kh + (size_t)gh * 147456;  // [n][d]
  const f16* Vg = Vh + (size_t)gh * 147456;  // [d][n]
  __shared__ alignas(16) f16 sQ[64 * 64];
  __shared__ alignas(16) f16 sK[2 * 64 * 64];
  __shared__ alignas(16) f16 sV[2 * 64 * 64];
  const int tid = threadIdx.x;
  const int wave = tid >> 6, lane = tid & 63, quad = lane >> 4, l16 = lane & 15;
  const floatx4 fzero = {0.f, 0.f, 0.f, 0.f};
  const int sw = l16 & 7;

  // stage Q + KV(0), swizzled source
  for (int p = 0; p < 4; ++p) {
    int e = p * 128 + tid;
    int row = e >> 3, cb = e & 7, sc = ((cb ^ (row & 7)) << 3);
    async_cp16(Qg + (size_t)(m0 + row) * 64 + sc, (char*)sQ + e * 16);
    async_cp16(Kg + (size_t)row * 64 + sc, (char*)sK + e * 16);
    async_cp16(Vg + (size_t)row * 2304 + sc, (char*)sV + e * 16);
  }
  __syncthreads();

  half8 qa[2][2];
  for (int s = 0; s < 2; ++s) {
    int qrow = wave * 32 + s * 16 + l16;
    qa[s][0] = *(const half8*)&sQ[qrow * 64 + ((quad ^ sw) << 3)];
    qa[s][1] = *(const half8*)&sQ[qrow * 64 + (((4 + quad) ^ sw) << 3)];
  }

  // prefetch KV(1)
  for (int p = 0; p < 4; ++p) {
    int e = p * 128 + tid;
    int row = e >> 3, cb = e & 7, sc = ((cb ^ (row & 7)) << 3);
    async_cp16(Kg + (size_t)(64 + row) * 64 + sc, (char*)(sK + 4096) + e * 16);
    async_cp16(Vg + (size_t)row * 2304 + 64 + sc, (char*)(sV + 4096) + e * 16);
  }

  float l_lane[2] = {0.f, 0.f};
  floatx4 o[2][4];
  for (int s = 0; s < 2; ++s)
    for (int dt = 0; dt < 4; ++dt) o[s][dt] = fzero;

  for (int kt = 0; kt < 36; ++kt) {
    const f16* bK = sK + (kt & 1) * 4096;
    const f16* bV = sV + (kt & 1) * 4096;

    // S^T: mfma(K,Q) -> S^T[n=quad*4+r][m=l16]; exp2 -> P frags (K=16 A-layout)
    half4 pf[2][4];
    for (int nt = 0; nt < 4; ++nt) {
      int krow = nt * 16 + l16;
      half8 kb0 = *(const half8*)&bK[krow * 64 + ((quad ^ sw) << 3)];
      half8 kb1 = *(const half8*)&bK[krow * 64 + (((4 + quad) ^ sw) << 3)];
      for (int s = 0; s < 2; ++s) {
        floatx4 t = __builtin_amdgcn_mfma_f32_16x16x32_f16(kb0, qa[s][0], fzero, 0, 0, 0);
        t = __builtin_amdgcn_mfma_f32_16x16x32_f16(kb1, qa[s][1], t, 0, 0, 0);
        for (int r = 0; r < 4; ++r) {
          float e = __builtin_amdgcn_exp2f(t[r]);
          l_lane[s] += e;
          pf[s][nt][r] = (f16)e;
        }
      }
    }
    // PV: o[m][d] += P . V ; V^T B-frags read once, used by both m-subtiles
    for (int dt = 0; dt < 4; ++dt) {
      int vrow = dt * 16 + l16;
      for (int nt = 0; nt < 4; ++nt) {
        int chunk = nt * 2 + (quad >> 1);
        half4 vb = *(const half4*)&bV[vrow * 64 + ((chunk ^ sw) << 3) + (quad & 1) * 4];
        for (int s = 0; s < 2; ++s)
          o[s][dt] = __builtin_amdgcn_mfma_f32_16x16x16f16(pf[s][nt], vb, o[s][dt], 0, 0, 0);
      }
    }

    if (kt < 35) {
      __syncthreads();
      if (kt + 2 < 36) {
        const int n0 = (kt + 2) * 64;
        char* dK = (char*)(sK + (kt & 1) * 4096);
        char* dV = (char*)(sV + (kt & 1) * 4096);
        for (int p = 0; p < 4; ++p) {
          int e = p * 128 + tid;
          int row = e >> 3, cb = e & 7, sc = ((cb ^ (row & 7)) << 3);
          async_cp16(Kg + (size_t)(n0 + row) * 64 + sc, dK + e * 16);
          async_cp16(Vg + (size_t)row * 2304 + n0 + sc, dV + e * 16);
        }
      }
    }
  }

  // row sums: combine quads, then broadcast per output row
  for (int s = 0; s < 2; ++s) {
    l_lane[s] += __shfl_xor(l_lane[s], 16, 64);
    l_lane[s] += __shfl_xor(l_lane[s], 32, 64);
  }
  for (int s = 0; s < 2; ++s) {
    float inv[4];
    for (int r = 0; r < 4; ++r) {
      float lr = __shfl(l_lane[s], quad * 4 + r, 64);
      inv[r] = 1.f / lr;
    }
    for (int dt = 0; dt < 4; ++dt)
      for (int r = 0; r < 4; ++r) {
        int n_tok = m0 + wave * 32 + s * 16 + quad * 4 + r;
        int v = n_tok / 576, hw = n_tok % 576;
        int bb = g * 4 + v;
        int c = h * 64 + dt * 16 + l16;
        AOT[((size_t)bb * 576 + hw) * 512 + c] = (f16)(o[s][dt][r] * inv[r]);
      }
  }
}

// ---------------- proj GEMM: out[b][o][hw] = WP[o][:] . AOT[t][:] + bias[o] ----------------
__global__ __launch_bounds__(256) void k_proj_gemm(const f16* __restrict__ AOT,
                                                   const f16* __restrict__ WP,
                                                   const float* __restrict__ bias,
                                                   float* __restrict__ out) {
  const int o0 = blockIdx.x * 128, t0 = blockIdx.y * 128;
  __shared__ alignas(16) f16 sA[128 * 64];
  __shared__ alignas(16) f16 sB[128 * 64];
  const int tid = threadIdx.x;
  const int wave = tid >> 6, lane = tid & 63, quad = lane >> 4, l16 = lane & 15;
  const int msub = (wave & 1) * 64, nsub = (wave >> 1) * 64;
  const floatx4 fzero = {0.f, 0.f, 0.f, 0.f};
  floatx4 acc[4][4];
  for (int i = 0; i < 4; ++i)
    for (int j = 0; j < 4; ++j) acc[i][j] = fzero;

  for (int k0 = 0; k0 < 512; k0 += 64) {
    __syncthreads();
    for (int p = 0; p < 4; ++p) {
      int e = p * 256 + tid;
      int row = e >> 3, colb = e & 7;
      async_cp16((const char*)WP + ((size_t)(o0 + row) * 512 + k0 + colb * 8) * 2,
                 (char*)sA + e * 16);
      async_cp16((const char*)AOT + ((size_t)(t0 + row) * 512 + k0 + colb * 8) * 2,
                 (char*)sB + e * 16);
    }
    __syncthreads();
    for (int f = 0; f < 2; ++f) {
      half8 a[4], bfr[4];
      for (int ms = 0; ms < 4; ++ms)
        a[ms] = *(const half8*)&sA[(msub + ms * 16 + l16) * 64 + f * 32 + quad * 8];
      for (int ns = 0; ns < 4; ++ns)
        bfr[ns] = *(const half8*)&sB[(nsub + ns * 16 + l16) * 64 + f * 32 + quad * 8];
      for (int ms = 0; ms < 4; ++ms)
        for (int ns = 0; ns < 4; ++ns)
          acc[ms][ns] =
              __builtin_amdgcn_mfma_f32_16x16x32_f16(a[ms], bfr[ns], acc[ms][ns], 0, 0, 0);
    }
  }
  for (int ms = 0; ms < 4; ++ms) {
    int o_row = o0 + msub + ms * 16 + quad * 4;
    for (int ns = 0; ns < 4; ++ns) {
      int t = t0 + nsub + ns * 16 + l16;
      int b = t / 576, hw = t % 576;
      for (int r = 0; r < 4; ++r) {
        int orow = o_row + r;
        out[(size_t)b * 294912 + (size_t)orow * 576 + hw] = acc[ms][ns][r] + bias[orow];
      }
    }
  }
}

extern "C" void kernel_launch(void* const* d_in, const int* in_sizes, int n_in,
                              void* d_out, int out_size, void* d_ws, size_t ws_size,
                              hipStream_t stream) {
  const float* x = (const float*)d_in[0];
  const float* wqkv = (const float*)d_in[1];
  const float* wproj = (const float*)d_in[2];
  const float* bias = (const float*)d_in[3];
  float* out = (float*)d_out;
  char* ws = (char*)d_ws;
  f16* XT = (f16*)(ws + 0);          // 4,718,592
  f16* WQ = (f16*)(ws + 4718592);    // 1,572,864
  f16* WP = (f16*)(ws + 6291456);    //   524,288
  f16* Qh = (f16*)(ws + 6815744);    // 4,718,592
  f16* Kh = (f16*)(ws + 11534336);   // 4,718,592
  f16* Vh = (f16*)(ws + 16252928);   // 4,718,592  ([gh][d][n], written by qkv directly)
  f16* AOT = (f16*)(ws + 20971520);  // 4,718,592

  k_prep<<<dim3(704), dim3(256), 0, stream>>>(x, XT, wqkv, wproj, WQ, WP);
  k_qkv_gemm<<<dim3(36, 12), dim3(256), 0, stream>>>(XT, WQ, Qh, Kh, Vh);
  k_attn<<<dim3(36, 16), dim3(128), 0, stream>>>(Qh, Kh, Vh, AOT);
  k_proj_gemm<<<dim3(4, 36), dim3(256), 0, stream>>>(AOT, WP, bias, out);
}

// Round 5
// 154.944 us; speedup vs baseline: 1.0445x; 1.0445x over previous
//
#include <hip/hip_runtime.h>
#include <stdint.h>

typedef _Float16 f16;
typedef _Float16 half8 __attribute__((ext_vector_type(8)));
typedef _Float16 half4 __attribute__((ext_vector_type(4)));
typedef float floatx4 __attribute__((ext_vector_type(4)));

#define LOG2E 1.44269504088896340736f

// async global->LDS, 16B per lane. LDS dest must be wave-uniform base + lane*16.
__device__ __forceinline__ void async_cp16(const void* g, void* l) {
  __builtin_amdgcn_global_load_lds((const __attribute__((address_space(1))) void*)g,
                                   (__attribute__((address_space(3))) void*)l, 16, 0, 0);
}

// ---------------- fused prep: x transpose->fp16 + weight convert ----------------
__global__ __launch_bounds__(256) void k_prep(const float* __restrict__ x,
                                              f16* __restrict__ XT,
                                              const float* __restrict__ wqkv,
                                              const float* __restrict__ wproj,
                                              f16* __restrict__ WQ, f16* __restrict__ WP) {
  __shared__ f16 sT[64][72];
  const int bid = blockIdx.x;
  const int tid = threadIdx.x;
  if (bid < 576) {
    const int hw0 = (bid % 9) * 64, c0 = ((bid / 9) & 7) * 64, b = bid / 72;
    const int cc = tid >> 6, hwc = tid & 63;
    const float* xb = x + (size_t)b * 294912;
    for (int i = 0; i < 16; ++i) {
      int c = c0 + i * 4 + cc;
      sT[hwc][i * 4 + cc] = (f16)xb[c * 576 + hw0 + hwc];
    }
    __syncthreads();
    const int c_c = tid & 63, rr = tid >> 6;
    f16* xtb = XT + ((size_t)b * 576 + hw0) * 512 + c0;
    for (int j = 0; j < 16; ++j) {
      int r = j * 4 + rr;
      xtb[(size_t)r * 512 + c_c] = sT[r][c_c];
    }
  } else {
    const float SCALE_Q = 0.125f * LOG2E;
    const int total1 = 1536 * 512, total2 = 512 * 512;
    for (int idx = (bid - 576) * 256 + tid; idx < total1 + total2; idx += 128 * 256) {
      if (idx < total1) {
        int row = idx >> 9;
        float v = wqkv[idx];
        if ((row % 192) < 64) v *= SCALE_Q;
        WQ[idx] = (f16)v;
      } else {
        WP[idx - total1] = (f16)wproj[idx - total1];
      }
    }
  }
}

// ---------------- QKV GEMM: D[t][row] = XT[t][:] . WQ[row][:] ----------------
__global__ __launch_bounds__(256) void k_qkv_gemm(const f16* __restrict__ XT,
                                                  const f16* __restrict__ WQ,
                                                  f16* __restrict__ Qh, f16* __restrict__ Kh,
                                                  f16* __restrict__ Vh) {
  const int t0 = blockIdx.x * 128, n0 = blockIdx.y * 128;
  __shared__ alignas(16) f16 smem[2 * 128 * 64];
  f16* sA = smem;
  f16* sB = smem + 128 * 64;
  const int tid = threadIdx.x;
  const int wave = tid >> 6, lane = tid & 63, quad = lane >> 4, l16 = lane & 15;
  const int msub = (wave & 1) * 64, nsub = (wave >> 1) * 64;
  const floatx4 fzero = {0.f, 0.f, 0.f, 0.f};
  floatx4 acc[4][4];
  for (int i = 0; i < 4; ++i)
    for (int j = 0; j < 4; ++j) acc[i][j] = fzero;

  for (int k0 = 0; k0 < 512; k0 += 64) {
    __syncthreads();
    for (int p = 0; p < 4; ++p) {
      int e = p * 256 + tid;
      int row = e >> 3, colb = e & 7;
      async_cp16((const char*)XT + ((size_t)(t0 + row) * 512 + k0 + colb * 8) * 2,
                 (char*)sA + e * 16);
      async_cp16((const char*)WQ + ((size_t)(n0 + row) * 512 + k0 + colb * 8) * 2,
                 (char*)sB + e * 16);
    }
    __syncthreads();
    for (int f = 0; f < 2; ++f) {
      half8 a[4], bfr[4];
      for (int ms = 0; ms < 4; ++ms)
        a[ms] = *(const half8*)&sA[(msub + ms * 16 + l16) * 64 + f * 32 + quad * 8];
      for (int ns = 0; ns < 4; ++ns)
        bfr[ns] = *(const half8*)&sB[(nsub + ns * 16 + l16) * 64 + f * 32 + quad * 8];
      for (int ms = 0; ms < 4; ++ms)
        for (int ns = 0; ns < 4; ++ns)
          acc[ms][ns] =
              __builtin_amdgcn_mfma_f32_16x16x32_f16(a[ms], bfr[ns], acc[ms][ns], 0, 0, 0);
    }
  }
  for (int ms = 0; ms < 4; ++ms) {
    int tbase = t0 + msub + ms * 16 + quad * 4;
    for (int ns = 0; ns < 4; ++ns) {
      int row = n0 + nsub + ns * 16 + l16;
      int h = row / 192, rr2 = row % 192;
      int sel = rr2 >> 6, d = rr2 & 63;
      if (sel == 2) continue;
      for (int r = 0; r < 4; ++r) {
        int t = tbase + r;
        int b = t / 576, hw = t % 576;
        int g = b >> 2, v = b & 3;
        int n = v * 576 + hw;
        int gh = g * 8 + h;
        f16 hv = (f16)acc[ms][ns][r];
        size_t idx = ((size_t)gh * 2304 + n) * 64 + d;
        if (sel == 0)
          Qh[idx] = hv;
        else
          Kh[idx] = hv;
      }
    }
  }
  const int r0 = n0 % 192;
  if (r0 != 0) {
    const int vloc = (r0 == 128) ? 0 : 64;
    const int h = (n0 + vloc) / 192;
    f16* sVT = smem;
    __syncthreads();
    if ((wave >> 1) == (vloc >> 6)) {
      for (int ms = 0; ms < 4; ++ms) {
        int tok = msub + ms * 16 + quad * 4;
        for (int ns = 0; ns < 4; ++ns) {
          int d = ns * 16 + l16;
          half4 hv;
          for (int r = 0; r < 4; ++r) hv[r] = (f16)acc[ms][ns][r];
          *(half4*)&sVT[d * 136 + tok] = hv;
        }
      }
    }
    __syncthreads();
    for (int pss = 0; pss < 4; ++pss) {
      int d = pss * 16 + (tid >> 4), chunk = tid & 15;
      int t = t0 + chunk * 8;
      int b = t / 576, hw = t - b * 576;
      int gh = (b >> 2) * 8 + h, n = (b & 3) * 576 + hw;
      *(half8*)(Vh + (size_t)gh * 147456 + (size_t)d * 2304 + n) =
          *(const half8*)&sVT[d * 136 + chunk * 8];
    }
  }
}

// ---------------- flash attention: 64 queries/block, key-split across wave pairs ----
// 4 waves: (wq = wave&1) -> queries wq*32..+32; (half = wave>>1) -> keys half*1152..+1152.
// No-max softmax => partials additive: waves 2,3 dump unnormalized O,l to LDS; waves
// 0,1 combine + normalize. Q direct global->reg. K/V double-buffered per key-stream.
__global__ __launch_bounds__(256) void k_attn(const f16* __restrict__ Qh,
                                              const f16* __restrict__ Kh,
                                              const f16* __restrict__ Vh,
                                              f16* __restrict__ AOT) {
  const int mt = blockIdx.x, gh = blockIdx.y;
  const int m0 = mt * 64;
  const int g = gh >> 3, h = gh & 7;
  const f16* Qg = Qh + (size_t)gh * 147456;  // [n][d]
  const f16* Kg = Kh + (size_t)gh * 147456;  // [n][d]
  const f16* Vg = Vh + (size_t)gh * 147456;  // [d][n]
  __shared__ alignas(16) f16 sK[2][2][64 * 64];  // [half][buf]
  __shared__ alignas(16) f16 sV[2][2][64 * 64];  // 64 KB total
  const int tid = threadIdx.x;
  const int wave = tid >> 6, lane = tid & 63, quad = lane >> 4, l16 = lane & 15;
  const int wq = wave & 1, half = wave >> 1;
  const floatx4 fzero = {0.f, 0.f, 0.f, 0.f};
  const int sw = l16 & 7;

  // stage K/V tile `ktile` (local index 0..17 within each half) into buf, both halves
  auto stage_kv = [&](int ktile, int buf) {
#pragma unroll
    for (int p = 0; p < 8; ++p) {
      const int half_t = (p >> 1) & 1, isV = p >> 2;
      int idx = (p & 1) * 256 + tid;
      int row = idx >> 3, cb = idx & 7, sc = ((cb ^ (row & 7)) << 3);
      int nb = half_t * 1152 + ktile * 64;
      if (!isV)
        async_cp16(Kg + (size_t)(nb + row) * 64 + sc, (char*)&sK[half_t][buf][0] + idx * 16);
      else
        async_cp16(Vg + (size_t)row * 2304 + nb + sc, (char*)&sV[half_t][buf][0] + idx * 16);
    }
  };

  // Q direct to registers (A-frag: m=l16, k=quad*8+j / +32)
  half8 qa[2][2];
  for (int s = 0; s < 2; ++s) {
    int qrow = m0 + wq * 32 + s * 16 + l16;
    qa[s][0] = *(const half8*)(Qg + (size_t)qrow * 64 + quad * 8);
    qa[s][1] = *(const half8*)(Qg + (size_t)qrow * 64 + 32 + quad * 8);
  }

  stage_kv(0, 0);
  __syncthreads();
  stage_kv(1, 1);

  float l_lane[2] = {0.f, 0.f};
  floatx4 o[2][4];
  for (int s = 0; s < 2; ++s)
    for (int dt = 0; dt < 4; ++dt) o[s][dt] = fzero;

  for (int kt = 0; kt < 18; ++kt) {
    const f16* bK = &sK[half][kt & 1][0];
    const f16* bV = &sV[half][kt & 1][0];

    half4 pf[2][4];
#pragma unroll
    for (int nt = 0; nt < 4; ++nt) {
      int krow = nt * 16 + l16;
      half8 kb0 = *(const half8*)&bK[krow * 64 + ((quad ^ sw) << 3)];
      half8 kb1 = *(const half8*)&bK[krow * 64 + (((4 + quad) ^ sw) << 3)];
#pragma unroll
      for (int s = 0; s < 2; ++s) {
        floatx4 t = __builtin_amdgcn_mfma_f32_16x16x32_f16(kb0, qa[s][0], fzero, 0, 0, 0);
        t = __builtin_amdgcn_mfma_f32_16x16x32_f16(kb1, qa[s][1], t, 0, 0, 0);
#pragma unroll
        for (int r = 0; r < 4; ++r) {
          float e = __builtin_amdgcn_exp2f(t[r]);
          l_lane[s] += e;
          pf[s][nt][r] = (f16)e;
        }
      }
    }
#pragma unroll
    for (int dt = 0; dt < 4; ++dt) {
      int vrow = dt * 16 + l16;
#pragma unroll
      for (int nt = 0; nt < 4; ++nt) {
        int chunk = nt * 2 + (quad >> 1);
        half4 vb = *(const half4*)&bV[vrow * 64 + ((chunk ^ sw) << 3) + (quad & 1) * 4];
#pragma unroll
        for (int s = 0; s < 2; ++s)
          o[s][dt] = __builtin_amdgcn_mfma_f32_16x16x16f16(pf[s][nt], vb, o[s][dt], 0, 0, 0);
      }
    }

    if (kt < 17) {
      __syncthreads();
      if (kt + 2 < 18) stage_kv(kt + 2, kt & 1);
    }
  }

  // combine halves via LDS (reuse sK for O, sV for l)
  __syncthreads();
  float* cO = (float*)sK;  // 16 KB used of 32
  float* cL = (float*)sV;  // 1 KB used of 32
  if (half == 1) {
    for (int s = 0; s < 2; ++s) {
      cL[(wq * 2 + s) * 64 + lane] = l_lane[s];
      for (int dt = 0; dt < 4; ++dt)
        *(floatx4*)&cO[((((wq * 2 + s) * 4 + dt) * 64 + lane) * 4)] = o[s][dt];
    }
  }
  __syncthreads();
  if (half == 0) {
    for (int s = 0; s < 2; ++s) {
      l_lane[s] += cL[(wq * 2 + s) * 64 + lane];
      for (int dt = 0; dt < 4; ++dt)
        o[s][dt] += *(const floatx4*)&cO[((((wq * 2 + s) * 4 + dt) * 64 + lane) * 4)];
    }
    for (int s = 0; s < 2; ++s) {
      l_lane[s] += __shfl_xor(l_lane[s], 16, 64);
      l_lane[s] += __shfl_xor(l_lane[s], 32, 64);
      float inv[4];
      for (int r = 0; r < 4; ++r) {
        float lr = __shfl(l_lane[s], quad * 4 + r, 64);
        inv[r] = 1.f / lr;
      }
      for (int dt = 0; dt < 4; ++dt)
        for (int r = 0; r < 4; ++r) {
          int n_tok = m0 + wq * 32 + s * 16 + quad * 4 + r;
          int v = n_tok / 576, hw = n_tok % 576;
          int bb = g * 4 + v;
          int c = h * 64 + dt * 16 + l16;
          AOT[((size_t)bb * 576 + hw) * 512 + c] = (f16)(o[s][dt][r] * inv[r]);
        }
    }
  }
}

// ---------------- proj GEMM: 64(o) x 128(t) tiles, grid 288 blocks ----------------
__global__ __launch_bounds__(256) void k_proj_gemm(const f16* __restrict__ AOT,
                                                   const f16* __restrict__ WP,
                                                   const float* __restrict__ bias,
                                                   float* __restrict__ out) {
  const int o0 = blockIdx.x * 64, t0 = blockIdx.y * 128;
  __shared__ alignas(16) f16 sA[64 * 64];   // [o][k]
  __shared__ alignas(16) f16 sB[128 * 64];  // [token][k]
  const int tid = threadIdx.x;
  const int wave = tid >> 6, lane = tid & 63, quad = lane >> 4, l16 = lane & 15;
  const int msub = (wave & 1) * 32, nsub = (wave >> 1) * 64;
  const floatx4 fzero = {0.f, 0.f, 0.f, 0.f};
  floatx4 acc[2][4];
  for (int i = 0; i < 2; ++i)
    for (int j = 0; j < 4; ++j) acc[i][j] = fzero;

  for (int k0 = 0; k0 < 512; k0 += 64) {
    __syncthreads();
    for (int p = 0; p < 2; ++p) {
      int e = p * 256 + tid;
      int row = e >> 3, colb = e & 7;
      async_cp16((const char*)WP + ((size_t)(o0 + row) * 512 + k0 + colb * 8) * 2,
                 (char*)sA + e * 16);
    }
    for (int p = 0; p < 4; ++p) {
      int e = p * 256 + tid;
      int row = e >> 3, colb = e & 7;
      async_cp16((const char*)AOT + ((size_t)(t0 + row) * 512 + k0 + colb * 8) * 2,
                 (char*)sB + e * 16);
    }
    __syncthreads();
    for (int f = 0; f < 2; ++f) {
      half8 a[2], bfr[4];
      for (int ms = 0; ms < 2; ++ms)
        a[ms] = *(const half8*)&sA[(msub + ms * 16 + l16) * 64 + f * 32 + quad * 8];
      for (int ns = 0; ns < 4; ++ns)
        bfr[ns] = *(const half8*)&sB[(nsub + ns * 16 + l16) * 64 + f * 32 + quad * 8];
      for (int ms = 0; ms < 2; ++ms)
        for (int ns = 0; ns < 4; ++ns)
          acc[ms][ns] =
              __builtin_amdgcn_mfma_f32_16x16x32_f16(a[ms], bfr[ns], acc[ms][ns], 0, 0, 0);
    }
  }
  for (int ms = 0; ms < 2; ++ms) {
    int o_row = o0 + msub + ms * 16 + quad * 4;
    for (int ns = 0; ns < 4; ++ns) {
      int t = t0 + nsub + ns * 16 + l16;
      int b = t / 576, hw = t % 576;
      for (int r = 0; r < 4; ++r) {
        int orow = o_row + r;
        out[(size_t)b * 294912 + (size_t)orow * 576 + hw] = acc[ms][ns][r] + bias[orow];
      }
    }
  }
}

extern "C" void kernel_launch(void* const* d_in, const int* in_sizes, int n_in,
                              void* d_out, int out_size, void* d_ws, size_t ws_size,
                              hipStream_t stream) {
  const float* x = (const float*)d_in[0];
  const float* wqkv = (const float*)d_in[1];
  const float* wproj = (const float*)d_in[2];
  const float* bias = (const float*)d_in[3];
  float* out = (float*)d_out;
  char* ws = (char*)d_ws;
  f16* XT = (f16*)(ws + 0);          // 4,718,592
  f16* WQ = (f16*)(ws + 4718592);    // 1,572,864
  f16* WP = (f16*)(ws + 6291456);    //   524,288
  f16* Qh = (f16*)(ws + 6815744);    // 4,718,592
  f16* Kh = (f16*)(ws + 11534336);   // 4,718,592
  f16* Vh = (f16*)(ws + 16252928);   // 4,718,592  ([gh][d][n])
  f16* AOT = (f16*)(ws + 20971520);  // 4,718,592

  k_prep<<<dim3(704), dim3(256), 0, stream>>>(x, XT, wqkv, wproj, WQ, WP);
  k_qkv_gemm<<<dim3(36, 12), dim3(256), 0, stream>>>(XT, WQ, Qh, Kh, Vh);
  k_attn<<<dim3(36, 16), dim3(256), 0, stream>>>(Qh, Kh, Vh, AOT);
  k_proj_gemm<<<dim3(8, 36), dim3(256), 0, stream>>>(AOT, WP, bias, out);
}